// Round 4
// baseline (204.936 us; speedup 1.0000x reference)
//
#include <hip/hip_runtime.h>
#include <math.h>

typedef unsigned short u16;
typedef unsigned int   u32;
typedef __attribute__((ext_vector_type(8))) short short8;
typedef __attribute__((ext_vector_type(4))) float f32x4;

namespace {
constexpr int Bb = 32, Nn = 32, Ll = 512, Mm = 64, Ff = 64;
constexpr int TL  = 32;           // K-tile in l (= one MFMA K step)
constexpr int NT  = Ll / TL;      // 16
constexpr int TLP = 40;           // padded row (u16): 80B stride
constexpr float EPSV = 1e-8f;
}

// One-instruction RNE pack: lo16 = bf16(a), hi16 = bf16(b).
__device__ __forceinline__ u32 cvt_pk_bf16(float a, float b) {
    u32 r;
    asm("v_cvt_pk_bf16_f32 %0, %1, %2" : "=v"(r) : "v"(a), "v"(b));
    return r;
}

// Split-precision pack of a pair: hw = packed bf16 hi parts, lw = packed bf16
// residuals (v - float(hi)).  6 VALU ops vs ~24 for the bit-twiddled version
// this replaces (round-3 post-mortem: packing was >half the staging VALU).
// Any 1-ulp rounding difference in hw is compensated by lw, so the hi+lo MFMA
// reconstruction keeps the same accuracy.
__device__ __forceinline__ void split2(float v0, float v1, u32& hw, u32& lw) {
    hw = cvt_pk_bf16(v0, v1);
    const float f0 = __uint_as_float(hw << 16);
    const float f1 = __uint_as_float(hw & 0xffff0000u);
    lw = cvt_pk_bf16(v0 - f0, v1 - f1);
}

// LDS-only barrier: global loads stay in flight across it (no vmcnt drain).
__device__ __forceinline__ void lgkm_barrier() {
    asm volatile("s_waitcnt lgkmcnt(0)" ::: "memory");
    __builtin_amdgcn_s_barrier();
    asm volatile("" ::: "memory");
}

// ---------------------------------------------------------------------------
// Round-2 structure (fused, dbuf LDS, swizzled x writes, lgkm barriers,
// depth-2 x register prefetch) with ALL bf16 packing routed through
// v_cvt_pk_bf16_f32.  Everything else byte-identical to round 2.
// ---------------------------------------------------------------------------
__global__ __launch_bounds__(256, 4)
void wagg_fused3(const float* __restrict__ x_aug,
                 const float* __restrict__ t_in,
                 const float* __restrict__ t_left,
                 const float* __restrict__ t_right,
                 const float* __restrict__ kappa,
                 float* __restrict__ out)
{
    const int n   = blockIdx.x & 31;
    const int b   = blockIdx.x >> 5;
    const int tid = threadIdx.x;

    __shared__ u16 ah_s[2][Mm * TLP];        // alpha-hi [m][l]   5 KB/stage
    __shared__ u16 al_s[2][Mm * TLP];        // alpha-lo
    __shared__ u16 xh_s[2][Ff * TLP];        // x-hi     [f][l-swizzled]
    __shared__ u16 xl_s[2][Ff * TLP];        // x-lo              total 40 KB

    // ---- x staging ids: lane strip over f, row pair over l ----
    const int fq  = tid & 15;                // f quad (f = 4*fq + j)
    const int lp2 = tid >> 4;                // 0..15 -> l = 2*lp2, 2*lp2+1
    // write swizzle: row r = 4*fq+j  =>  (r>>3)&3 == (fq>>1)&3 for all j
    const int sw    = (fq >> 1) & 3;
    const u32 wbase = (u32)(((lp2 >> 2) ^ sw) * 8 + (lp2 & 3) * 2);

    // ---- alpha ids: wave wv covers m in [wv*16, wv*16+16) ----
    const int wv   = tid >> 6;
    const int lane = tid & 63;
    const int ma   = wv * 16 + (lane >> 2);  // this thread's m
    const int lqa  = lane & 3;               // l chunk: l = lqa*8 + 0..7

    // ---- MFMA ids: wave = (m-half, f-half), 2x2 16x16 tiles ----
    const int mh = wv & 1;                   // m base = mh*32
    const int fh = wv >> 1;                  // f base = fh*32
    const int q  = lane >> 4;                // k-chunk / D-row-quad
    const int c  = lane & 15;                // A/B row select / D-col

    const float* xb = x_aug + (size_t)(b * Nn + n) * (Ll * Ff);

    // ---- prologue scalars ----
    const float kap = kappa[n];
    const float kk  = fmaxf(kap, 0.0f) + log1pf(expf(-fabsf(kap))); // softplus
    const float ik  = 1.0f / kk;
    const float tlv = t_left [n * Mm + ma];
    const float trv = t_right[n * Mm + ma];
    const float Ac  = __expf(-trv * ik);     // e^{-tr/k}
    const float Bc  = __expf( tlv * ik);     // e^{+tl/k}

    f32x4 acc[2][2];
    #pragma unroll
    for (int mi = 0; mi < 2; ++mi)
        #pragma unroll
        for (int fi = 0; fi < 2; ++fi)
            acc[mi][fi] = (f32x4){0.f, 0.f, 0.f, 0.f};

    float XA0[4], XA1[4], XB0[4], XB1[4];    // depth-2 parity prefetch sets
    float T[8];                              // t values (depth-1, L1-hot)
    float dsum = 0.0f;                       // fp32 denominator partial

#define LOADX(X0_, X1_, T_) { \
    const float* p_ = xb + (size_t)((T_) * TL + 2 * lp2) * Ff + fq * 4; \
    *(float4*)(X0_) = *(const float4*)p_; \
    *(float4*)(X1_) = *(const float4*)(p_ + Ff); }

#define LOADT(T_) { \
    *(float4*)&T[0] = *(const float4*)&t_in[(T_) * TL + lqa * 8]; \
    *(float4*)&T[4] = *(const float4*)&t_in[(T_) * TL + lqa * 8 + 4]; }

// stage (convert x + compute alpha) into buffer BUF_ from register set X0_/X1_
#define STAGEX(BUF_, X0_, X1_) { \
    _Pragma("unroll") \
    for (int j = 0; j < 4; ++j) { \
        u32 hw_, lw_; \
        split2((X0_)[j], (X1_)[j], hw_, lw_); \
        const u32 off_ = (u32)(fq * 4 + j) * TLP + wbase; \
        *(u32*)&xh_s[BUF_][off_] = hw_; \
        *(u32*)&xl_s[BUF_][off_] = lw_; } \
    u32 hi_[4], lo_[4]; \
    _Pragma("unroll") \
    for (int jj = 0; jj < 8; jj += 2) { \
        const float u0 = __expf(T[jj]     * ik); \
        const float u1 = __expf(T[jj + 1] * ik); \
        const float d0 = fmaf(Ac, u0, 1.0f) * (u0 + Bc); \
        const float d1 = fmaf(Ac, u1, 1.0f) * (u1 + Bc); \
        const float a0 = u0 * __builtin_amdgcn_rcpf(d0); \
        const float a1 = u1 * __builtin_amdgcn_rcpf(d1); \
        dsum += a0 + a1; \
        split2(a0, a1, hi_[jj >> 1], lo_[jj >> 1]); } \
    const u32 aoff_ = (u32)ma * TLP + lqa * 8; \
    *(uint4*)&ah_s[BUF_][aoff_] = make_uint4(hi_[0], hi_[1], hi_[2], hi_[3]); \
    *(uint4*)&al_s[BUF_][aoff_] = make_uint4(lo_[0], lo_[1], lo_[2], lo_[3]); }

// One K-tile: issue t+1 T-load and t+2 x-load early, read fragments, 12 MFMA,
// stage tile t+1 (x from XS set, alpha from T), lgkm-only barrier.
#define TILE(T_, CUR_, XS0_, XS1_, XL0_, XL1_) { \
    if ((T_) + 1 < NT) LOADT((T_) + 1); \
    if ((T_) + 2 < NT) LOADX(XL0_, XL1_, (T_) + 2); \
    short8 ahf[2], alf[2], xhf[2], xlf[2]; \
    _Pragma("unroll") \
    for (int mi = 0; mi < 2; ++mi) { \
        const u32 off_ = (u32)(mh * 32 + mi * 16 + c) * TLP + q * 8; \
        ahf[mi] = *(const short8*)&ah_s[CUR_][off_]; \
        alf[mi] = *(const short8*)&al_s[CUR_][off_]; } \
    _Pragma("unroll") \
    for (int fi = 0; fi < 2; ++fi) { \
        const int row_ = fh * 32 + fi * 16 + c; \
        const u32 off_ = (u32)row_ * TLP + (u32)((q ^ ((row_ >> 3) & 3)) * 8); \
        xhf[fi] = *(const short8*)&xh_s[CUR_][off_]; \
        xlf[fi] = *(const short8*)&xl_s[CUR_][off_]; } \
    _Pragma("unroll") \
    for (int mi = 0; mi < 2; ++mi) \
        _Pragma("unroll") \
        for (int fi = 0; fi < 2; ++fi) { \
            acc[mi][fi] = __builtin_amdgcn_mfma_f32_16x16x32_bf16(ahf[mi], xhf[fi], acc[mi][fi], 0, 0, 0); \
            acc[mi][fi] = __builtin_amdgcn_mfma_f32_16x16x32_bf16(ahf[mi], xlf[fi], acc[mi][fi], 0, 0, 0); \
            acc[mi][fi] = __builtin_amdgcn_mfma_f32_16x16x32_bf16(alf[mi], xhf[fi], acc[mi][fi], 0, 0, 0); } \
    if ((T_) + 1 < NT) STAGEX((CUR_) ^ 1, XS0_, XS1_); \
    lgkm_barrier(); }

    // ---- prologue: stage tile 0, start tile-1 loads ----
    LOADX(XA0, XA1, 0);
    LOADT(0);
    STAGEX(0, XA0, XA1);
    LOADX(XB0, XB1, 1);
    lgkm_barrier();

    // steady state: TILE(t) consumes buf[t&1]; stages t+1 from the set loaded
    // at t-1; issues load of t+2 into the set just freed.
    for (int tt = 0; tt < NT / 2; ++tt) {
        const int t0 = 2 * tt;
        TILE(t0,     0, XB0, XB1, XA0, XA1);
        TILE(t0 + 1, 1, XA0, XA1, XB0, XB1);
    }

#undef TILE
#undef STAGEX
#undef LOADT
#undef LOADX

    // ---- denominator reduce (alias freed stage buf 0) ----
    float* dred = (float*)&xh_s[0][0];       // 256 f32 partials
    float* invp = dred + 256;                // 64 f32 inverses (within 5 KB)
    dred[lqa * 64 + ma] = dsum;
    lgkm_barrier();
    if (tid < Mm) {
        const float d = dred[tid] + dred[64 + tid] + dred[128 + tid] + dred[192 + tid];
        invp[tid] = __builtin_amdgcn_rcpf(d + EPSV);
    }
    lgkm_barrier();

    // ---- epilogue: scale by 1/(denom+eps), store ----
    float* ob = out + (size_t)(b * Nn + n) * (Mm * Ff);
    #pragma unroll
    for (int mi = 0; mi < 2; ++mi) {
        const int mbase = mh * 32 + mi * 16 + q * 4;
        float iv[4];
        #pragma unroll
        for (int r = 0; r < 4; ++r) iv[r] = invp[mbase + r];
        #pragma unroll
        for (int fi = 0; fi < 2; ++fi) {
            const int f = fh * 32 + fi * 16 + c;
            #pragma unroll
            for (int r = 0; r < 4; ++r)
                ob[(size_t)(mbase + r) * Ff + f] = acc[mi][fi][r] * iv[r];
        }
    }
}

extern "C" void kernel_launch(void* const* d_in, const int* in_sizes, int n_in,
                              void* d_out, int out_size, void* d_ws, size_t ws_size,
                              hipStream_t stream)
{
    const float* x_aug   = (const float*)d_in[0];
    const float* t_in    = (const float*)d_in[1];
    const float* t_left  = (const float*)d_in[2];
    const float* t_right = (const float*)d_in[3];
    const float* kappa   = (const float*)d_in[4];
    float* out = (float*)d_out;

    hipLaunchKernelGGL(wagg_fused3, dim3(Bb * Nn), dim3(256), 0, stream,
                       x_aug, t_in, t_left, t_right, kappa, out);
}